// Round 4
// baseline (5450.077 us; speedup 1.0000x reference)
//
#include <hip/hip_runtime.h>
#include <hip/hip_bf16.h>

#define Bsz 256
#define Nd  512
#define Hd  2048
#define Td  64
#define OFF_T (Bsz * Td * Nd)
#define OFF_L (OFF_T + Td)
#define LDU 514   // Ulds stride: 1028B rows -> frag-read banks (lr+4lk)%32, ~2-way
#define LDZ 136

typedef __attribute__((ext_vector_type(8))) short short8;
typedef __attribute__((ext_vector_type(4))) float f32x4;

static __device__ __forceinline__ unsigned short f2bf(float x) {
  unsigned u = __builtin_bit_cast(unsigned, x);
  u += 0x7FFFu + ((u >> 16) & 1u);   // RNE
  return (unsigned short)(u >> 16);
}
static __device__ __forceinline__ float fast_tanh(float x) {
  float ex = __expf(2.0f * x);       // inf-safe
  return 1.0f - 2.0f / (ex + 1.0f);
}
static __device__ __forceinline__ unsigned long long lda64(const void* p) {
  return __hip_atomic_load((const unsigned long long*)p, __ATOMIC_RELAXED,
                           __HIP_MEMORY_SCOPE_AGENT);
}
static __device__ __forceinline__ void sta64(void* p, unsigned long long v) {
  __hip_atomic_store((unsigned long long*)p, v, __ATOMIC_RELAXED,
                     __HIP_MEMORY_SCOPE_AGENT);
}
// group barrier (16 blocks), monotonic counter, proven ACQ_REL/ACQUIRE pattern
static __device__ __forceinline__ void gbar(unsigned* ctr, unsigned target) {
  __syncthreads();
  if (threadIdx.x == 0) {
    __hip_atomic_fetch_add(ctr, 1u, __ATOMIC_ACQ_REL, __HIP_MEMORY_SCOPE_AGENT);
    while (__hip_atomic_load(ctr, __ATOMIC_ACQUIRE, __HIP_MEMORY_SCOPE_AGENT) < target)
      __builtin_amdgcn_s_sleep(1);
  }
  __syncthreads();
}

// 256 blocks x 256 threads (4 waves), 1 block/CU (LDS-forced).
// g = blk & 15  (m-slice group; members co-XCD under round-robin dispatch)
// l = blk >> 4  (member: H-slice in phase A, N-slice in phase B)
__launch_bounds__(256, 1)
__global__ void ode_2ph(const float* __restrict__ y0g, const float* __restrict__ te,
                        const float* __restrict__ W1, const float* __restrict__ b1,
                        const float* __restrict__ W2, const float* __restrict__ b2,
                        float* __restrict__ out, unsigned* __restrict__ bar,
                        float* __restrict__ kS, unsigned short* __restrict__ Zg) {
  __shared__ unsigned short Ulds[16 * LDU];
  __shared__ unsigned short Zlds[16 * LDZ];
  __shared__ float red[4][16][33];
  __shared__ char spad[56 * 1024];   // occupancy limiter: 1 block/CU

  const int blk = blockIdx.x;
  const int g = blk & 15, il = blk >> 4;
  const int tid = threadIdx.x;
  const int wv = tid >> 6, lane = tid & 63;
  const int lr = lane & 15, lk = lane >> 4;

  if (te[0] == 1.0e30f) {            // never true; keeps spad allocated
    ((volatile char*)spad)[tid] = (char)tid;
    out[0] = ((volatile char*)spad)[0];
  }

  // ---------- one-time: resident weight fragments ----------
  short8 w1f[2][16];                 // W1 slice: cols il*128 + wv*32 + n*16 + lr
  {
    const int hbase = il * 128 + wv * 32;
    #pragma unroll
    for (int n = 0; n < 2; ++n) {
      const int col = hbase + n * 16 + lr;
      #pragma unroll
      for (int kt = 0; kt < 16; ++kt) {
        short8 v;
        #pragma unroll
        for (int j = 0; j < 8; ++j)
          v[j] = (short)f2bf(W1[(kt * 32 + lk * 8 + j) * Hd + col]);
        w1f[n][kt] = v;
      }
    }
  }
  short8 w2f[2][16];                 // W2 slice: cols il*32 + n*16 + lr, K-chunk wv*512
  {
    #pragma unroll
    for (int n = 0; n < 2; ++n) {
      const int col = il * 32 + n * 16 + lr;
      #pragma unroll
      for (int kt = 0; kt < 16; ++kt) {
        short8 v;
        #pragma unroll
        for (int j = 0; j < 8; ++j)
          v[j] = (short)f2bf(W2[(wv * 512 + kt * 32 + lk * 8 + j) * Nd + col]);
        w2f[n][kt] = v;
      }
    }
  }
  float b1c[2];
  b1c[0] = b1[il * 128 + wv * 32 + lr];
  b1c[1] = b1[il * 128 + wv * 32 + 16 + lr];

  // ---------- per-thread state mapping ----------
  const int r  = tid >> 4;           // local m-row
  const int cq = tid & 15;
  const int cb = cq * 32;            // 32-col N chunk
  const int rowg = g * 16 + r;       // global batch row
  const int c2 = (tid & 15) * 2;     // export pair within il's 32-col slice
  const int rowe = tid >> 4;
  const float b2e0 = b2[il * 32 + c2], b2e1 = b2[il * 32 + c2 + 1];

  float yv[32];
  #pragma unroll
  for (int gg = 0; gg < 8; ++gg) {
    f32x4 v = *(const f32x4*)&y0g[rowg * Nd + cb + gg * 4];
    yv[gg * 4 + 0] = v[0]; yv[gg * 4 + 1] = v[1];
    yv[gg * 4 + 2] = v[2]; yv[gg * 4 + 3] = v[3];
  }
  float acc_y[32];
  #pragma unroll
  for (int p = 0; p < 32; ++p) acc_y[p] = 0.0f;

  // ---------- pre-loop outputs ----------
  if (cq == il) {
    #pragma unroll
    for (int gg = 0; gg < 8; ++gg) {
      f32x4 v = {yv[gg * 4], yv[gg * 4 + 1], yv[gg * 4 + 2], yv[gg * 4 + 3]};
      *(f32x4*)&out[rowg * (Td * Nd) + cb + gg * 4] = v;
    }
  }
  if (blk == 0) {
    if (tid < Td) out[OFF_T + tid] = te[tid];
    out[OFF_L + tid] = 0.0f;
  }

  unsigned* ctr = bar + g * 64;      // 256B-spaced per-group counter

  // ---------- main loop: 63 steps x 4 evals, 2 phases each ----------
  int j = 0;
  for (int t = 0; t < Td - 1; ++t) {
    const float h = te[t + 1] - te[t];
    for (int e = 1; e <= 4; ++e) {
      // ======== PHASE A: U -> GEMM1 -> tanh -> Z export ========
      if (e == 1) {
        if (t > 0) {
          const float hp6 = (te[t] - te[t - 1]) * (1.0f / 6.0f);
          #pragma unroll
          for (int gg = 0; gg < 4; ++gg) {
            #pragma unroll
            for (int p = 0; p < 4; ++p) {
              unsigned long long q = lda64(&kS[rowg * Nd + cb + gg * 8 + p * 2]);
              float k0 = __builtin_bit_cast(float, (unsigned)(q & 0xFFFFFFFFull));
              float k1 = __builtin_bit_cast(float, (unsigned)(q >> 32));
              yv[gg * 8 + p * 2 + 0] += hp6 * (acc_y[gg * 8 + p * 2 + 0] + k0);
              yv[gg * 8 + p * 2 + 1] += hp6 * (acc_y[gg * 8 + p * 2 + 1] + k1);
            }
          }
          if (cq == il) {
            #pragma unroll
            for (int gg = 0; gg < 8; ++gg) {
              f32x4 v = {yv[gg * 4], yv[gg * 4 + 1], yv[gg * 4 + 2], yv[gg * 4 + 3]};
              *(f32x4*)&out[rowg * (Td * Nd) + t * Nd + cb + gg * 4] = v;
            }
          }
        }
        #pragma unroll
        for (int p = 0; p < 32; ++p) acc_y[p] = 0.0f;
        #pragma unroll
        for (int gg = 0; gg < 4; ++gg) {
          short8 s;
          #pragma unroll
          for (int p = 0; p < 8; ++p) s[p] = (short)f2bf(yv[gg * 8 + p]);
          *(short8*)&Ulds[r * LDU + cb + gg * 8] = s;
        }
      } else {
        const float c = (e == 4) ? h : 0.5f * h;
        const float w = (e == 2) ? 1.0f : 2.0f;
        #pragma unroll
        for (int gg = 0; gg < 4; ++gg) {
          short8 s;
          #pragma unroll
          for (int p = 0; p < 4; ++p) {
            unsigned long long q = lda64(&kS[rowg * Nd + cb + gg * 8 + p * 2]);
            float k0 = __builtin_bit_cast(float, (unsigned)(q & 0xFFFFFFFFull));
            float k1 = __builtin_bit_cast(float, (unsigned)(q >> 32));
            acc_y[gg * 8 + p * 2 + 0] += w * k0;
            acc_y[gg * 8 + p * 2 + 1] += w * k1;
            s[p * 2 + 0] = (short)f2bf(yv[gg * 8 + p * 2 + 0] + c * k0);
            s[p * 2 + 1] = (short)f2bf(yv[gg * 8 + p * 2 + 1] + c * k1);
          }
          *(short8*)&Ulds[r * LDU + cb + gg * 8] = s;
        }
      }
      __syncthreads();

      // GEMM1: [16,512] @ W1-slice -> 32 H-cols/wave
      f32x4 acc1_0 = {0.f, 0.f, 0.f, 0.f}, acc1_1 = {0.f, 0.f, 0.f, 0.f};
      {
        const int abase = lr * LDU + lk * 8;
        #pragma unroll
        for (int kt = 0; kt < 16; ++kt) {
          short8 a = *(const short8*)&Ulds[abase + kt * 32];
          acc1_0 = __builtin_amdgcn_mfma_f32_16x16x32_bf16(a, w1f[0][kt], acc1_0, 0, 0, 0);
          acc1_1 = __builtin_amdgcn_mfma_f32_16x16x32_bf16(a, w1f[1][kt], acc1_1, 0, 0, 0);
        }
      }
      #pragma unroll
      for (int n = 0; n < 2; ++n) {
        f32x4 a = n ? acc1_1 : acc1_0;
        #pragma unroll
        for (int q = 0; q < 4; ++q)
          Zlds[(lk * 4 + q) * LDZ + wv * 32 + n * 16 + lr] = f2bf(fast_tanh(a[q] + b1c[n]));
      }
      __syncthreads();
      // export Z[16,128] bf16 -> Zg (coalesced u64 agent stores)
      #pragma unroll
      for (int u = 0; u < 2; ++u) {
        int idx = tid + u * 256;            // 0..511
        int zr = idx >> 5, zc4 = idx & 31;  // row, 4-col group
        unsigned long long v = *(const unsigned long long*)&Zlds[zr * LDZ + zc4 * 4];
        sta64(&Zg[(g * 16 + zr) * Hd + il * 128 + zc4 * 4], v);
      }
      gbar(ctr, (unsigned)(2 * j + 1) * 16);

      // ======== PHASE B: k[16,32] = Z[16,2048] @ W2-slice (split-K by wave) ========
      f32x4 acc2_0 = {0.f, 0.f, 0.f, 0.f}, acc2_1 = {0.f, 0.f, 0.f, 0.f};
      {
        const unsigned short* zp = &Zg[(g * 16 + lr) * Hd + wv * 512 + lk * 8];
        #pragma unroll
        for (int kt = 0; kt < 16; ++kt) {
          union { unsigned long long q[2]; short8 s; } az;
          az.q[0] = lda64(zp + kt * 32);
          az.q[1] = lda64(zp + kt * 32 + 4);
          acc2_0 = __builtin_amdgcn_mfma_f32_16x16x32_bf16(az.s, w2f[0][kt], acc2_0, 0, 0, 0);
          acc2_1 = __builtin_amdgcn_mfma_f32_16x16x32_bf16(az.s, w2f[1][kt], acc2_1, 0, 0, 0);
        }
      }
      // deterministic cross-wave reduce via LDS
      #pragma unroll
      for (int q = 0; q < 4; ++q) {
        red[wv][lk * 4 + q][lr]      = acc2_0[q];
        red[wv][lk * 4 + q][16 + lr] = acc2_1[q];
      }
      __syncthreads();
      {
        float s0 = red[0][rowe][c2] + red[1][rowe][c2] + red[2][rowe][c2] + red[3][rowe][c2] + b2e0;
        float s1 = red[0][rowe][c2 + 1] + red[1][rowe][c2 + 1] + red[2][rowe][c2 + 1] + red[3][rowe][c2 + 1] + b2e1;
        unsigned long long pk =
            ((unsigned long long)__builtin_bit_cast(unsigned, s1) << 32) |
            __builtin_bit_cast(unsigned, s0);
        sta64(&kS[(g * 16 + rowe) * Nd + il * 32 + c2], pk);
      }
      gbar(ctr, (unsigned)(2 * j + 2) * 16);
      ++j;
    }
  }

  // ---------- epilogue: final y-update + y_t[:, 63, :] ----------
  {
    const float hp6 = (te[Td - 1] - te[Td - 2]) * (1.0f / 6.0f);
    #pragma unroll
    for (int gg = 0; gg < 4; ++gg) {
      #pragma unroll
      for (int p = 0; p < 4; ++p) {
        unsigned long long q = lda64(&kS[rowg * Nd + cb + gg * 8 + p * 2]);
        float k0 = __builtin_bit_cast(float, (unsigned)(q & 0xFFFFFFFFull));
        float k1 = __builtin_bit_cast(float, (unsigned)(q >> 32));
        yv[gg * 8 + p * 2 + 0] += hp6 * (acc_y[gg * 8 + p * 2 + 0] + k0);
        yv[gg * 8 + p * 2 + 1] += hp6 * (acc_y[gg * 8 + p * 2 + 1] + k1);
      }
    }
    if (cq == il) {
      #pragma unroll
      for (int gg = 0; gg < 8; ++gg) {
        f32x4 v = {yv[gg * 4], yv[gg * 4 + 1], yv[gg * 4 + 2], yv[gg * 4 + 3]};
        *(f32x4*)&out[rowg * (Td * Nd) + (Td - 1) * Nd + cb + gg * 4] = v;
      }
    }
  }
}

extern "C" void kernel_launch(void* const* d_in, const int* in_sizes, int n_in,
                              void* d_out, int out_size, void* d_ws, size_t ws_size,
                              hipStream_t stream) {
  const float* y0 = (const float*)d_in[0];
  const float* te = (const float*)d_in[1];
  const float* W1 = (const float*)d_in[2];
  const float* b1 = (const float*)d_in[3];
  const float* W2 = (const float*)d_in[4];
  const float* b2 = (const float*)d_in[5];
  float* out = (float*)d_out;

  unsigned* bar = (unsigned*)d_ws;                       // 16 groups x 64 u32 = 4KB
  float* kS = (float*)((char*)d_ws + 4096);              // [256][512] f32 = 512KB
  unsigned short* Zg = (unsigned short*)((char*)d_ws + 4096 + 512 * 1024);  // [256][2048] bf16 = 1MB

  hipMemsetAsync(bar, 0, 4096, stream);                  // reset barrier counters
  ode_2ph<<<dim3(256), dim3(256), 0, stream>>>(y0, te, W1, b1, W2, b2, out, bar, kS, Zg);
}

// Round 5
// 4719.825 us; speedup vs baseline: 1.1547x; 1.1547x over previous
//
#include <hip/hip_runtime.h>
#include <hip/hip_bf16.h>

#define Bsz 256
#define Nd  512
#define Hd  2048
#define Td  64
#define OFF_T (Bsz * Td * Nd)
#define OFF_L (OFF_T + Td)
#define LDU 514   // Ulds stride: 1028B rows -> frag-read banks (lr+4lk)%32, ~2-way
#define LDZ 136

typedef __attribute__((ext_vector_type(8))) short short8;
typedef __attribute__((ext_vector_type(4))) float f32x4;

static __device__ __forceinline__ unsigned short f2bf(float x) {
  unsigned u = __builtin_bit_cast(unsigned, x);
  u += 0x7FFFu + ((u >> 16) & 1u);   // RNE
  return (unsigned short)(u >> 16);
}
static __device__ __forceinline__ float fast_tanh(float x) {
  float ex = __expf(2.0f * x);       // inf-safe
  return 1.0f - 2.0f / (ex + 1.0f);
}
static __device__ __forceinline__ unsigned long long lda64(const void* p) {
  return __hip_atomic_load((const unsigned long long*)p, __ATOMIC_RELAXED,
                           __HIP_MEMORY_SCOPE_AGENT);
}
static __device__ __forceinline__ void sta64(void* p, unsigned long long v) {
  __hip_atomic_store((unsigned long long*)p, v, __ATOMIC_RELAXED,
                     __HIP_MEMORY_SCOPE_AGENT);
}
// group barrier (16 blocks): RELEASE arrival, RELAXED spin (no per-poll
// L2-invalidate!), single ACQUIRE fence on exit.
static __device__ __forceinline__ void gbar(unsigned* ctr, unsigned target) {
  __syncthreads();
  if (threadIdx.x == 0) {
    __hip_atomic_fetch_add(ctr, 1u, __ATOMIC_RELEASE, __HIP_MEMORY_SCOPE_AGENT);
    while (__hip_atomic_load(ctr, __ATOMIC_RELAXED, __HIP_MEMORY_SCOPE_AGENT) < target)
      __builtin_amdgcn_s_sleep(2);
    __builtin_amdgcn_fence(__ATOMIC_ACQUIRE, "agent");   // one invalidate per barrier
  }
  __syncthreads();
}

// 256 blocks x 256 threads (4 waves), 1 block/CU (LDS-forced).
// g = blk & 15  (m-slice group; members co-XCD under round-robin dispatch)
// l = blk >> 4  (member: H-slice in phase A, N-slice in phase B)
__launch_bounds__(256, 1)
__global__ void ode_2ph(const float* __restrict__ y0g, const float* __restrict__ te,
                        const float* __restrict__ W1, const float* __restrict__ b1,
                        const float* __restrict__ W2, const float* __restrict__ b2,
                        float* __restrict__ out, unsigned* __restrict__ bar,
                        float* __restrict__ kS, unsigned short* __restrict__ Zg) {
  __shared__ unsigned short Ulds[16 * LDU];
  __shared__ unsigned short Zlds[16 * LDZ];
  __shared__ float red[4][16][33];
  __shared__ char spad[56 * 1024];   // occupancy limiter: 1 block/CU

  const int blk = blockIdx.x;
  const int g = blk & 15, il = blk >> 4;
  const int tid = threadIdx.x;
  const int wv = tid >> 6, lane = tid & 63;
  const int lr = lane & 15, lk = lane >> 4;

  if (te[0] == 1.0e30f) {            // never true; keeps spad allocated
    ((volatile char*)spad)[tid] = (char)tid;
    out[0] = ((volatile char*)spad)[0];
  }

  // ---------- one-time: resident weight fragments ----------
  short8 w1f[2][16];                 // W1 slice: cols il*128 + wv*32 + n*16 + lr
  {
    const int hbase = il * 128 + wv * 32;
    #pragma unroll
    for (int n = 0; n < 2; ++n) {
      const int col = hbase + n * 16 + lr;
      #pragma unroll
      for (int kt = 0; kt < 16; ++kt) {
        short8 v;
        #pragma unroll
        for (int j = 0; j < 8; ++j)
          v[j] = (short)f2bf(W1[(kt * 32 + lk * 8 + j) * Hd + col]);
        w1f[n][kt] = v;
      }
    }
  }
  short8 w2f[2][16];                 // W2 slice: cols il*32 + n*16 + lr, K-chunk wv*512
  {
    #pragma unroll
    for (int n = 0; n < 2; ++n) {
      const int col = il * 32 + n * 16 + lr;
      #pragma unroll
      for (int kt = 0; kt < 16; ++kt) {
        short8 v;
        #pragma unroll
        for (int j = 0; j < 8; ++j)
          v[j] = (short)f2bf(W2[(wv * 512 + kt * 32 + lk * 8 + j) * Nd + col]);
        w2f[n][kt] = v;
      }
    }
  }
  float b1c[2];
  b1c[0] = b1[il * 128 + wv * 32 + lr];
  b1c[1] = b1[il * 128 + wv * 32 + 16 + lr];

  // ---------- per-thread state mapping ----------
  const int r  = tid >> 4;           // local m-row
  const int cq = tid & 15;
  const int cb = cq * 32;            // 32-col N chunk
  const int rowg = g * 16 + r;       // global batch row
  const int c2 = (tid & 15) * 2;     // export pair within il's 32-col slice
  const int rowe = tid >> 4;
  const float b2e0 = b2[il * 32 + c2], b2e1 = b2[il * 32 + c2 + 1];

  float yv[32];
  #pragma unroll
  for (int gg = 0; gg < 8; ++gg) {
    f32x4 v = *(const f32x4*)&y0g[rowg * Nd + cb + gg * 4];
    yv[gg * 4 + 0] = v[0]; yv[gg * 4 + 1] = v[1];
    yv[gg * 4 + 2] = v[2]; yv[gg * 4 + 3] = v[3];
  }
  float acc_y[32];
  #pragma unroll
  for (int p = 0; p < 32; ++p) acc_y[p] = 0.0f;

  // ---------- pre-loop outputs ----------
  if (cq == il) {
    #pragma unroll
    for (int gg = 0; gg < 8; ++gg) {
      f32x4 v = {yv[gg * 4], yv[gg * 4 + 1], yv[gg * 4 + 2], yv[gg * 4 + 3]};
      *(f32x4*)&out[rowg * (Td * Nd) + cb + gg * 4] = v;
    }
  }
  if (blk == 0) {
    if (tid < Td) out[OFF_T + tid] = te[tid];
    out[OFF_L + tid] = 0.0f;
  }

  unsigned* ctr = bar + g * 64;      // 256B-spaced per-group counter

  // ---------- main loop: 63 steps x 4 evals, 2 phases each ----------
  int j = 0;
  for (int t = 0; t < Td - 1; ++t) {
    const float h = te[t + 1] - te[t];
    for (int e = 1; e <= 4; ++e) {
      // ======== PHASE A: U -> GEMM1 -> tanh -> Z export ========
      if (e == 1) {
        if (t > 0) {
          const float hp6 = (te[t] - te[t - 1]) * (1.0f / 6.0f);
          #pragma unroll
          for (int gg = 0; gg < 4; ++gg) {
            #pragma unroll
            for (int p = 0; p < 4; ++p) {
              unsigned long long q = lda64(&kS[rowg * Nd + cb + gg * 8 + p * 2]);
              float k0 = __builtin_bit_cast(float, (unsigned)(q & 0xFFFFFFFFull));
              float k1 = __builtin_bit_cast(float, (unsigned)(q >> 32));
              yv[gg * 8 + p * 2 + 0] += hp6 * (acc_y[gg * 8 + p * 2 + 0] + k0);
              yv[gg * 8 + p * 2 + 1] += hp6 * (acc_y[gg * 8 + p * 2 + 1] + k1);
            }
          }
          if (cq == il) {
            #pragma unroll
            for (int gg = 0; gg < 8; ++gg) {
              f32x4 v = {yv[gg * 4], yv[gg * 4 + 1], yv[gg * 4 + 2], yv[gg * 4 + 3]};
              *(f32x4*)&out[rowg * (Td * Nd) + t * Nd + cb + gg * 4] = v;
            }
          }
        }
        #pragma unroll
        for (int p = 0; p < 32; ++p) acc_y[p] = 0.0f;
        #pragma unroll
        for (int gg = 0; gg < 4; ++gg) {
          short8 s;
          #pragma unroll
          for (int p = 0; p < 8; ++p) s[p] = (short)f2bf(yv[gg * 8 + p]);
          *(short8*)&Ulds[r * LDU + cb + gg * 8] = s;
        }
      } else {
        const float c = (e == 4) ? h : 0.5f * h;
        const float w = (e == 2) ? 1.0f : 2.0f;
        #pragma unroll
        for (int gg = 0; gg < 4; ++gg) {
          short8 s;
          #pragma unroll
          for (int p = 0; p < 4; ++p) {
            unsigned long long q = lda64(&kS[rowg * Nd + cb + gg * 8 + p * 2]);
            float k0 = __builtin_bit_cast(float, (unsigned)(q & 0xFFFFFFFFull));
            float k1 = __builtin_bit_cast(float, (unsigned)(q >> 32));
            acc_y[gg * 8 + p * 2 + 0] += w * k0;
            acc_y[gg * 8 + p * 2 + 1] += w * k1;
            s[p * 2 + 0] = (short)f2bf(yv[gg * 8 + p * 2 + 0] + c * k0);
            s[p * 2 + 1] = (short)f2bf(yv[gg * 8 + p * 2 + 1] + c * k1);
          }
          *(short8*)&Ulds[r * LDU + cb + gg * 8] = s;
        }
      }
      __syncthreads();

      // GEMM1: [16,512] @ W1-slice -> 32 H-cols/wave
      f32x4 acc1_0 = {0.f, 0.f, 0.f, 0.f}, acc1_1 = {0.f, 0.f, 0.f, 0.f};
      {
        const int abase = lr * LDU + lk * 8;
        #pragma unroll
        for (int kt = 0; kt < 16; ++kt) {
          short8 a = *(const short8*)&Ulds[abase + kt * 32];
          acc1_0 = __builtin_amdgcn_mfma_f32_16x16x32_bf16(a, w1f[0][kt], acc1_0, 0, 0, 0);
          acc1_1 = __builtin_amdgcn_mfma_f32_16x16x32_bf16(a, w1f[1][kt], acc1_1, 0, 0, 0);
        }
      }
      #pragma unroll
      for (int n = 0; n < 2; ++n) {
        f32x4 a = n ? acc1_1 : acc1_0;
        #pragma unroll
        for (int q = 0; q < 4; ++q)
          Zlds[(lk * 4 + q) * LDZ + wv * 32 + n * 16 + lr] = f2bf(fast_tanh(a[q] + b1c[n]));
      }
      __syncthreads();
      // export Z[16,128] bf16 -> Zg (coalesced u64 agent stores)
      #pragma unroll
      for (int u = 0; u < 2; ++u) {
        int idx = tid + u * 256;            // 0..511
        int zr = idx >> 5, zc4 = idx & 31;  // row, 4-col group
        unsigned long long v = *(const unsigned long long*)&Zlds[zr * LDZ + zc4 * 4];
        sta64(&Zg[(g * 16 + zr) * Hd + il * 128 + zc4 * 4], v);
      }
      gbar(ctr, (unsigned)(2 * j + 1) * 16);

      // ======== PHASE B: k[16,32] = Z[16,2048] @ W2-slice (split-K by wave) ========
      f32x4 acc2_0 = {0.f, 0.f, 0.f, 0.f}, acc2_1 = {0.f, 0.f, 0.f, 0.f};
      {
        const unsigned short* zp = &Zg[(g * 16 + lr) * Hd + wv * 512 + lk * 8];
        #pragma unroll
        for (int kt = 0; kt < 16; ++kt) {
          union { unsigned long long q[2]; short8 s; } az;
          az.q[0] = lda64(zp + kt * 32);
          az.q[1] = lda64(zp + kt * 32 + 4);
          acc2_0 = __builtin_amdgcn_mfma_f32_16x16x32_bf16(az.s, w2f[0][kt], acc2_0, 0, 0, 0);
          acc2_1 = __builtin_amdgcn_mfma_f32_16x16x32_bf16(az.s, w2f[1][kt], acc2_1, 0, 0, 0);
        }
      }
      // deterministic cross-wave reduce via LDS
      #pragma unroll
      for (int q = 0; q < 4; ++q) {
        red[wv][lk * 4 + q][lr]      = acc2_0[q];
        red[wv][lk * 4 + q][16 + lr] = acc2_1[q];
      }
      __syncthreads();
      {
        float s0 = red[0][rowe][c2] + red[1][rowe][c2] + red[2][rowe][c2] + red[3][rowe][c2] + b2e0;
        float s1 = red[0][rowe][c2 + 1] + red[1][rowe][c2 + 1] + red[2][rowe][c2 + 1] + red[3][rowe][c2 + 1] + b2e1;
        unsigned long long pk =
            ((unsigned long long)__builtin_bit_cast(unsigned, s1) << 32) |
            __builtin_bit_cast(unsigned, s0);
        sta64(&kS[(g * 16 + rowe) * Nd + il * 32 + c2], pk);
      }
      gbar(ctr, (unsigned)(2 * j + 2) * 16);
      ++j;
    }
  }

  // ---------- epilogue: final y-update + y_t[:, 63, :] ----------
  {
    const float hp6 = (te[Td - 1] - te[Td - 2]) * (1.0f / 6.0f);
    #pragma unroll
    for (int gg = 0; gg < 4; ++gg) {
      #pragma unroll
      for (int p = 0; p < 4; ++p) {
        unsigned long long q = lda64(&kS[rowg * Nd + cb + gg * 8 + p * 2]);
        float k0 = __builtin_bit_cast(float, (unsigned)(q & 0xFFFFFFFFull));
        float k1 = __builtin_bit_cast(float, (unsigned)(q >> 32));
        yv[gg * 8 + p * 2 + 0] += hp6 * (acc_y[gg * 8 + p * 2 + 0] + k0);
        yv[gg * 8 + p * 2 + 1] += hp6 * (acc_y[gg * 8 + p * 2 + 1] + k1);
      }
    }
    if (cq == il) {
      #pragma unroll
      for (int gg = 0; gg < 8; ++gg) {
        f32x4 v = {yv[gg * 4], yv[gg * 4 + 1], yv[gg * 4 + 2], yv[gg * 4 + 3]};
        *(f32x4*)&out[rowg * (Td * Nd) + (Td - 1) * Nd + cb + gg * 4] = v;
      }
    }
  }
}

extern "C" void kernel_launch(void* const* d_in, const int* in_sizes, int n_in,
                              void* d_out, int out_size, void* d_ws, size_t ws_size,
                              hipStream_t stream) {
  const float* y0 = (const float*)d_in[0];
  const float* te = (const float*)d_in[1];
  const float* W1 = (const float*)d_in[2];
  const float* b1 = (const float*)d_in[3];
  const float* W2 = (const float*)d_in[4];
  const float* b2 = (const float*)d_in[5];
  float* out = (float*)d_out;

  unsigned* bar = (unsigned*)d_ws;                       // 16 groups x 64 u32 = 4KB
  float* kS = (float*)((char*)d_ws + 4096);              // [256][512] f32 = 512KB
  unsigned short* Zg = (unsigned short*)((char*)d_ws + 4096 + 512 * 1024);  // [256][2048] bf16 = 1MB

  hipMemsetAsync(bar, 0, 4096, stream);                  // reset barrier counters
  ode_2ph<<<dim3(256), dim3(256), 0, stream>>>(y0, te, W1, b1, W2, b2, out, bar, kS, Zg);
}

// Round 6
// 2909.880 us; speedup vs baseline: 1.8730x; 1.6220x over previous
//
#include <hip/hip_runtime.h>
#include <hip/hip_bf16.h>

#define Bsz 256
#define Nd  512
#define Hd  2048
#define Td  64
#define OFF_T (Bsz * Td * Nd)
#define OFF_L (OFF_T + Td)
#define LDU 514   // Ulds stride: 1028B rows -> frag-read banks (lr+4lk)%32, ~2-way
#define LDZ 136

typedef __attribute__((ext_vector_type(8))) short short8;
typedef __attribute__((ext_vector_type(4))) float f32x4;

static __device__ __forceinline__ unsigned short f2bf(float x) {
  unsigned u = __builtin_bit_cast(unsigned, x);
  u += 0x7FFFu + ((u >> 16) & 1u);   // RNE
  return (unsigned short)(u >> 16);
}
static __device__ __forceinline__ float fast_tanh(float x) {
  float ex = __expf(2.0f * x);       // inf-safe
  return 1.0f - 2.0f / (ex + 1.0f);
}
static __device__ __forceinline__ unsigned long long lda64(const void* p) {
  return __hip_atomic_load((const unsigned long long*)p, __ATOMIC_RELAXED,
                           __HIP_MEMORY_SCOPE_AGENT);
}
static __device__ __forceinline__ void sta64(void* p, unsigned long long v) {
  __hip_atomic_store((unsigned long long*)p, v, __ATOMIC_RELAXED,
                     __HIP_MEMORY_SCOPE_AGENT);
}
// group barrier (16 blocks): FULLY RELAXED — no buffer_wbl2, no buffer_inv.
// Safe because ALL cross-block data moves via agent-scope (sc1, LLC-direct)
// atomics, and __syncthreads() drains vmcnt(0) so those stores are at the
// LLC before the counter RMW lands there. Poll liveness in rounds 3-5
// proves sc1 loads bypass L2 (per-XCD L2s are never probed).
static __device__ __forceinline__ void gbar(unsigned* ctr, unsigned target) {
  __syncthreads();
  if (threadIdx.x == 0) {
    __hip_atomic_fetch_add(ctr, 1u, __ATOMIC_RELAXED, __HIP_MEMORY_SCOPE_AGENT);
    while (__hip_atomic_load(ctr, __ATOMIC_RELAXED, __HIP_MEMORY_SCOPE_AGENT) < target)
      __builtin_amdgcn_s_sleep(2);
    asm volatile("" ::: "memory");   // compiler-only barrier (no cache ops)
  }
  __syncthreads();
}

// 256 blocks x 256 threads (4 waves), 1 block/CU (LDS-forced).
// g = blk & 15  (m-slice group; members co-XCD under round-robin dispatch)
// l = blk >> 4  (member: H-slice in phase A, N-slice in phase B)
__launch_bounds__(256, 1)
__global__ void ode_2ph(const float* __restrict__ y0g, const float* __restrict__ te,
                        const float* __restrict__ W1, const float* __restrict__ b1,
                        const float* __restrict__ W2, const float* __restrict__ b2,
                        float* __restrict__ out, unsigned* __restrict__ bar,
                        float* __restrict__ kS, unsigned short* __restrict__ Zg) {
  __shared__ unsigned short Ulds[16 * LDU];
  __shared__ unsigned short Zlds[16 * LDZ];
  __shared__ float red[4][16][33];
  __shared__ char spad[56 * 1024];   // occupancy limiter: 1 block/CU

  const int blk = blockIdx.x;
  const int g = blk & 15, il = blk >> 4;
  const int tid = threadIdx.x;
  const int wv = tid >> 6, lane = tid & 63;
  const int lr = lane & 15, lk = lane >> 4;

  if (te[0] == 1.0e30f) {            // never true; keeps spad allocated
    ((volatile char*)spad)[tid] = (char)tid;
    out[0] = ((volatile char*)spad)[0];
  }

  // ---------- one-time: resident weight fragments ----------
  short8 w1f[2][16];                 // W1 slice: cols il*128 + wv*32 + n*16 + lr
  {
    const int hbase = il * 128 + wv * 32;
    #pragma unroll
    for (int n = 0; n < 2; ++n) {
      const int col = hbase + n * 16 + lr;
      #pragma unroll
      for (int kt = 0; kt < 16; ++kt) {
        short8 v;
        #pragma unroll
        for (int j = 0; j < 8; ++j)
          v[j] = (short)f2bf(W1[(kt * 32 + lk * 8 + j) * Hd + col]);
        w1f[n][kt] = v;
      }
    }
  }
  short8 w2f[2][16];                 // W2 slice: cols il*32 + n*16 + lr, K-chunk wv*512
  {
    #pragma unroll
    for (int n = 0; n < 2; ++n) {
      const int col = il * 32 + n * 16 + lr;
      #pragma unroll
      for (int kt = 0; kt < 16; ++kt) {
        short8 v;
        #pragma unroll
        for (int j = 0; j < 8; ++j)
          v[j] = (short)f2bf(W2[(wv * 512 + kt * 32 + lk * 8 + j) * Nd + col]);
        w2f[n][kt] = v;
      }
    }
  }
  float b1c[2];
  b1c[0] = b1[il * 128 + wv * 32 + lr];
  b1c[1] = b1[il * 128 + wv * 32 + 16 + lr];

  // ---------- per-thread state mapping ----------
  const int r  = tid >> 4;           // local m-row
  const int cq = tid & 15;
  const int cb = cq * 32;            // 32-col N chunk
  const int rowg = g * 16 + r;       // global batch row
  const int c2 = (tid & 15) * 2;     // export pair within il's 32-col slice
  const int rowe = tid >> 4;
  const float b2e0 = b2[il * 32 + c2], b2e1 = b2[il * 32 + c2 + 1];

  float yv[32];
  #pragma unroll
  for (int gg = 0; gg < 8; ++gg) {
    f32x4 v = *(const f32x4*)&y0g[rowg * Nd + cb + gg * 4];
    yv[gg * 4 + 0] = v[0]; yv[gg * 4 + 1] = v[1];
    yv[gg * 4 + 2] = v[2]; yv[gg * 4 + 3] = v[3];
  }
  float acc_y[32];
  #pragma unroll
  for (int p = 0; p < 32; ++p) acc_y[p] = 0.0f;

  // ---------- pre-loop outputs ----------
  if (cq == il) {
    #pragma unroll
    for (int gg = 0; gg < 8; ++gg) {
      f32x4 v = {yv[gg * 4], yv[gg * 4 + 1], yv[gg * 4 + 2], yv[gg * 4 + 3]};
      *(f32x4*)&out[rowg * (Td * Nd) + cb + gg * 4] = v;
    }
  }
  if (blk == 0) {
    if (tid < Td) out[OFF_T + tid] = te[tid];
    out[OFF_L + tid] = 0.0f;
  }

  unsigned* ctr = bar + g * 64;      // 256B-spaced per-group counter

  // ---------- main loop: 63 steps x 4 evals, 2 phases each ----------
  int j = 0;
  for (int t = 0; t < Td - 1; ++t) {
    const float h = te[t + 1] - te[t];
    for (int e = 1; e <= 4; ++e) {
      // ======== PHASE A: U -> GEMM1 -> tanh -> Z export ========
      if (e == 1) {
        if (t > 0) {
          const float hp6 = (te[t] - te[t - 1]) * (1.0f / 6.0f);
          #pragma unroll
          for (int gg = 0; gg < 4; ++gg) {
            #pragma unroll
            for (int p = 0; p < 4; ++p) {
              unsigned long long q = lda64(&kS[rowg * Nd + cb + gg * 8 + p * 2]);
              float k0 = __builtin_bit_cast(float, (unsigned)(q & 0xFFFFFFFFull));
              float k1 = __builtin_bit_cast(float, (unsigned)(q >> 32));
              yv[gg * 8 + p * 2 + 0] += hp6 * (acc_y[gg * 8 + p * 2 + 0] + k0);
              yv[gg * 8 + p * 2 + 1] += hp6 * (acc_y[gg * 8 + p * 2 + 1] + k1);
            }
          }
          if (cq == il) {
            #pragma unroll
            for (int gg = 0; gg < 8; ++gg) {
              f32x4 v = {yv[gg * 4], yv[gg * 4 + 1], yv[gg * 4 + 2], yv[gg * 4 + 3]};
              *(f32x4*)&out[rowg * (Td * Nd) + t * Nd + cb + gg * 4] = v;
            }
          }
        }
        #pragma unroll
        for (int p = 0; p < 32; ++p) acc_y[p] = 0.0f;
        #pragma unroll
        for (int gg = 0; gg < 4; ++gg) {
          short8 s;
          #pragma unroll
          for (int p = 0; p < 8; ++p) s[p] = (short)f2bf(yv[gg * 8 + p]);
          *(short8*)&Ulds[r * LDU + cb + gg * 8] = s;
        }
      } else {
        const float c = (e == 4) ? h : 0.5f * h;
        const float w = (e == 2) ? 1.0f : 2.0f;
        #pragma unroll
        for (int gg = 0; gg < 4; ++gg) {
          short8 s;
          #pragma unroll
          for (int p = 0; p < 4; ++p) {
            unsigned long long q = lda64(&kS[rowg * Nd + cb + gg * 8 + p * 2]);
            float k0 = __builtin_bit_cast(float, (unsigned)(q & 0xFFFFFFFFull));
            float k1 = __builtin_bit_cast(float, (unsigned)(q >> 32));
            acc_y[gg * 8 + p * 2 + 0] += w * k0;
            acc_y[gg * 8 + p * 2 + 1] += w * k1;
            s[p * 2 + 0] = (short)f2bf(yv[gg * 8 + p * 2 + 0] + c * k0);
            s[p * 2 + 1] = (short)f2bf(yv[gg * 8 + p * 2 + 1] + c * k1);
          }
          *(short8*)&Ulds[r * LDU + cb + gg * 8] = s;
        }
      }
      __syncthreads();

      // GEMM1: [16,512] @ W1-slice -> 32 H-cols/wave
      f32x4 acc1_0 = {0.f, 0.f, 0.f, 0.f}, acc1_1 = {0.f, 0.f, 0.f, 0.f};
      {
        const int abase = lr * LDU + lk * 8;
        #pragma unroll
        for (int kt = 0; kt < 16; ++kt) {
          short8 a = *(const short8*)&Ulds[abase + kt * 32];
          acc1_0 = __builtin_amdgcn_mfma_f32_16x16x32_bf16(a, w1f[0][kt], acc1_0, 0, 0, 0);
          acc1_1 = __builtin_amdgcn_mfma_f32_16x16x32_bf16(a, w1f[1][kt], acc1_1, 0, 0, 0);
        }
      }
      #pragma unroll
      for (int n = 0; n < 2; ++n) {
        f32x4 a = n ? acc1_1 : acc1_0;
        #pragma unroll
        for (int q = 0; q < 4; ++q)
          Zlds[(lk * 4 + q) * LDZ + wv * 32 + n * 16 + lr] = f2bf(fast_tanh(a[q] + b1c[n]));
      }
      __syncthreads();
      // export Z[16,128] bf16 -> Zg (coalesced u64 agent stores)
      #pragma unroll
      for (int u = 0; u < 2; ++u) {
        int idx = tid + u * 256;            // 0..511
        int zr = idx >> 5, zc4 = idx & 31;  // row, 4-col group
        unsigned long long v = *(const unsigned long long*)&Zlds[zr * LDZ + zc4 * 4];
        sta64(&Zg[(g * 16 + zr) * Hd + il * 128 + zc4 * 4], v);
      }
      gbar(ctr, (unsigned)(2 * j + 1) * 16);

      // ======== PHASE B: k[16,32] = Z[16,2048] @ W2-slice (split-K by wave) ========
      f32x4 acc2_0 = {0.f, 0.f, 0.f, 0.f}, acc2_1 = {0.f, 0.f, 0.f, 0.f};
      {
        const unsigned short* zp = &Zg[(g * 16 + lr) * Hd + wv * 512 + lk * 8];
        #pragma unroll
        for (int kt = 0; kt < 16; ++kt) {
          union { unsigned long long q[2]; short8 s; } az;
          az.q[0] = lda64(zp + kt * 32);
          az.q[1] = lda64(zp + kt * 32 + 4);
          acc2_0 = __builtin_amdgcn_mfma_f32_16x16x32_bf16(az.s, w2f[0][kt], acc2_0, 0, 0, 0);
          acc2_1 = __builtin_amdgcn_mfma_f32_16x16x32_bf16(az.s, w2f[1][kt], acc2_1, 0, 0, 0);
        }
      }
      // deterministic cross-wave reduce via LDS
      #pragma unroll
      for (int q = 0; q < 4; ++q) {
        red[wv][lk * 4 + q][lr]      = acc2_0[q];
        red[wv][lk * 4 + q][16 + lr] = acc2_1[q];
      }
      __syncthreads();
      {
        float s0 = red[0][rowe][c2] + red[1][rowe][c2] + red[2][rowe][c2] + red[3][rowe][c2] + b2e0;
        float s1 = red[0][rowe][c2 + 1] + red[1][rowe][c2 + 1] + red[2][rowe][c2 + 1] + red[3][rowe][c2 + 1] + b2e1;
        unsigned long long pk =
            ((unsigned long long)__builtin_bit_cast(unsigned, s1) << 32) |
            __builtin_bit_cast(unsigned, s0);
        sta64(&kS[(g * 16 + rowe) * Nd + il * 32 + c2], pk);
      }
      gbar(ctr, (unsigned)(2 * j + 2) * 16);
      ++j;
    }
  }

  // ---------- epilogue: final y-update + y_t[:, 63, :] ----------
  {
    const float hp6 = (te[Td - 1] - te[Td - 2]) * (1.0f / 6.0f);
    #pragma unroll
    for (int gg = 0; gg < 4; ++gg) {
      #pragma unroll
      for (int p = 0; p < 4; ++p) {
        unsigned long long q = lda64(&kS[rowg * Nd + cb + gg * 8 + p * 2]);
        float k0 = __builtin_bit_cast(float, (unsigned)(q & 0xFFFFFFFFull));
        float k1 = __builtin_bit_cast(float, (unsigned)(q >> 32));
        yv[gg * 8 + p * 2 + 0] += hp6 * (acc_y[gg * 8 + p * 2 + 0] + k0);
        yv[gg * 8 + p * 2 + 1] += hp6 * (acc_y[gg * 8 + p * 2 + 1] + k1);
      }
    }
    if (cq == il) {
      #pragma unroll
      for (int gg = 0; gg < 8; ++gg) {
        f32x4 v = {yv[gg * 4], yv[gg * 4 + 1], yv[gg * 4 + 2], yv[gg * 4 + 3]};
        *(f32x4*)&out[rowg * (Td * Nd) + (Td - 1) * Nd + cb + gg * 4] = v;
      }
    }
  }
}

extern "C" void kernel_launch(void* const* d_in, const int* in_sizes, int n_in,
                              void* d_out, int out_size, void* d_ws, size_t ws_size,
                              hipStream_t stream) {
  const float* y0 = (const float*)d_in[0];
  const float* te = (const float*)d_in[1];
  const float* W1 = (const float*)d_in[2];
  const float* b1 = (const float*)d_in[3];
  const float* W2 = (const float*)d_in[4];
  const float* b2 = (const float*)d_in[5];
  float* out = (float*)d_out;

  unsigned* bar = (unsigned*)d_ws;                       // 16 groups x 64 u32 = 4KB
  float* kS = (float*)((char*)d_ws + 4096);              // [256][512] f32 = 512KB
  unsigned short* Zg = (unsigned short*)((char*)d_ws + 4096 + 512 * 1024);  // [256][2048] bf16 = 1MB

  hipMemsetAsync(bar, 0, 4096, stream);                  // reset barrier counters
  ode_2ph<<<dim3(256), dim3(256), 0, stream>>>(y0, te, W1, b1, W2, b2, out, bar, kS, Zg);
}